// Round 5
// baseline (157.979 us; speedup 1.0000x reference)
//
#include <hip/hip_runtime.h>
#include <math.h>

#define BB 32
#define TT 1024
#define HH 128

typedef __attribute__((ext_vector_type(8))) short short8;
typedef __attribute__((ext_vector_type(4))) float floatx4;

__device__ __forceinline__ unsigned short f2bf(float f) {
    unsigned u = __float_as_uint(f);
    u += 0x7fffu + ((u >> 16) & 1u);
    return (unsigned short)(u >> 16);
}

// Kernel A: gather embedding rows, normalize (store bf16), compute lambda.
// 32 lanes per row (float4 loads), 2 rows per wave, 8 rows per block.
__global__ __launch_bounds__(256)
void gather_norm(const int* __restrict__ seq,
                 const float* __restrict__ embd,
                 const float* __restrict__ lam_w,
                 const float* __restrict__ lam_b,
                 unsigned short* __restrict__ xbf,
                 float* __restrict__ lam) {
    const int lane = threadIdx.x & 63;
    const int half = lane >> 5;
    const int l32  = lane & 31;
    const int row  = blockIdx.x * 8 + (threadIdx.x >> 6) * 2 + half;
    const int idx  = seq[row];
    float4 v = ((const float4*)(embd + (size_t)idx * HH))[l32];
    float4 w = ((const float4*)lam_w)[l32];
    float ss = v.x * v.x + v.y * v.y + v.z * v.z + v.w * v.w;
    float dw = v.x * w.x + v.y * w.y + v.z * w.z + v.w * w.w;
    #pragma unroll
    for (int off = 16; off > 0; off >>= 1) {
        ss += __shfl_xor(ss, off);
        dw += __shfl_xor(dw, off);
    }
    float inv = 1.0f / sqrtf(ss);
    unsigned b0 = f2bf(v.x * inv), b1 = f2bf(v.y * inv);
    unsigned b2 = f2bf(v.z * inv), b3 = f2bf(v.w * inv);
    uint2 o; o.x = b0 | (b1 << 16); o.y = b2 | (b3 << 16);
    ((uint2*)(xbf + (size_t)row * HH))[l32] = o;
    if (l32 == 0) lam[row] = expf(dw + lam_b[0]);
}

// Kernel B1: ONE WAVE per (b, t-tile, chunk). A chunk = 4 s-tiles = 64 s
// values. Every active wave does exactly 4 unconditional MFMA tiles (the
// s<t mask zeroes anything past the diagonal; all loads stay in-bounds).
// Wave emits per-t partials (W, Y, T = chunk sim total) to ws; chunks are
// merged in kernel B2 with the associative rescale exp(-lam * T_above).
__global__ __launch_bounds__(256)
void sim_part(const unsigned short* __restrict__ xbf,
              const float* __restrict__ lam,
              const float* __restrict__ y,
              float* __restrict__ Wp,
              float* __restrict__ Yp,
              float* __restrict__ Tp) {
    const int wid  = blockIdx.x * 4 + (threadIdx.x >> 6);  // 0..32767
    const int c    = wid & 15;            // chunk index (s-tiles 4c..4c+3)
    const int tt   = (wid >> 4) & 63;     // t-tile
    const int b    = wid >> 10;
    const int lane = threadIdx.x & 63;
    const int tl   = lane & 15;
    const int quad = lane >> 4;
    const int pi   = wid * 16 + tl;       // partial index

    if (4 * c > tt) {                     // chunk entirely above diagonal
        if (quad == 0) { Wp[pi] = 0.f; Yp[pi] = 0.f; Tp[pi] = 0.f; }
        return;
    }

    const int t = tt * 16 + tl;
    const size_t rowbase = (size_t)b * TT;
    const float lam_t = lam[rowbase + t];
    const float* yb = y + rowbase;

    // preload Xq fragments (B operand), 4 K-steps of 32
    short8 bq[4];
    const short8* qrow = (const short8*)(xbf + (rowbase + t) * HH);
    #pragma unroll
    for (int kk = 0; kk < 4; kk++) bq[kk] = qrow[kk * 4 + quad];

    float vv[4][4];
    float tT[4], hq[4];

    // ---- phase A: sims + per-tile totals (independent across 4 tiles) ----
    #pragma unroll
    for (int j = 0; j < 4; j++) {
        const int s_base = (c * 4 + j) << 4;
        const short8* arow =
            (const short8*)(xbf + (rowbase + s_base + tl) * HH);
        floatx4 acc = {0.f, 0.f, 0.f, 0.f};
        #pragma unroll
        for (int kk = 0; kk < 4; kk++) {
            short8 af = arow[kk * 4 + quad];
            acc = __builtin_amdgcn_mfma_f32_16x16x32_bf16(af, bq[kk], acc, 0, 0, 0);
        }
        const int s0g = s_base + quad * 4;
        float v0 = (s0g + 0 < t) ? (acc[0] + 1.f) * 0.5f : 0.f;
        float v1 = (s0g + 1 < t) ? (acc[1] + 1.f) * 0.5f : 0.f;
        float v2 = (s0g + 2 < t) ? (acc[2] + 1.f) * 0.5f : 0.f;
        float v3 = (s0g + 3 < t) ? (acc[3] + 1.f) * 0.5f : 0.f;
        vv[j][0] = v0; vv[j][1] = v1; vv[j][2] = v2; vv[j][3] = v3;
        float ts = (v0 + v1) + (v2 + v3);
        float q0 = __shfl(ts, tl);
        float q1 = __shfl(ts, tl + 16);
        float q2 = __shfl(ts, tl + 32);
        float q3 = __shfl(ts, tl + 48);
        tT[j] = (q0 + q1) + (q2 + q3);
        hq[j] = (quad < 1 ? q1 : 0.f) + (quad < 2 ? q2 : 0.f) +
                (quad < 3 ? q3 : 0.f);
    }

    // ---- chunk-local suffix of tile totals (tile 3 = highest s) ----
    float d3 = hq[3];
    float d2 = hq[2] + tT[3];
    float d1 = hq[1] + (tT[2] + tT[3]);
    float d0 = hq[0] + (tT[1] + (tT[2] + tT[3]));
    float Ttot = (tT[0] + tT[1]) + (tT[2] + tT[3]);
    float dbase[4] = {d0, d1, d2, d3};

    // ---- phase B: weights (independent across tiles) ----
    float wsum = 0.f, wy = 0.f;
    #pragma unroll
    for (int j = 0; j < 4; j++) {
        const int s_base = (c * 4 + j) << 4;
        float v0 = vv[j][0], v1 = vv[j][1], v2 = vv[j][2], v3 = vv[j][3];
        float suf3 = v3;
        float suf2 = v2 + suf3;
        float suf1 = v1 + suf2;
        float suf0 = v0 + suf1;
        float db = dbase[j];
        float4 yv = ((const float4*)(yb + s_base))[quad];
        float w0 = v0 * __expf(-lam_t * (suf0 + db));
        float w1 = v1 * __expf(-lam_t * (suf1 + db));
        float w2 = v2 * __expf(-lam_t * (suf2 + db));
        float w3 = v3 * __expf(-lam_t * (suf3 + db));
        wsum += (w0 + w1) + (w2 + w3);
        wy   += w0 * yv.x + w1 * yv.y + w2 * yv.z + w3 * yv.w;
    }

    // ---- reduce across quads, store partials ----
    float Wt = __shfl(wsum, tl) + __shfl(wsum, tl + 16) +
               __shfl(wsum, tl + 32) + __shfl(wsum, tl + 48);
    float Yt = __shfl(wy, tl) + __shfl(wy, tl + 16) +
               __shfl(wy, tl + 32) + __shfl(wy, tl + 48);
    if (quad == 0) {
        Wp[pi] = Wt;
        Yp[pi] = Yt;
        Tp[pi] = Ttot;   // per-t, uniform across quads
    }
}

// Kernel B2: merge the 16 chunk partials per (b, t). One thread per t.
__global__ __launch_bounds__(256)
void merge_kernel(const float* __restrict__ Wp,
                  const float* __restrict__ Yp,
                  const float* __restrict__ Tp,
                  const float* __restrict__ lam,
                  float* __restrict__ out) {
    const int id = blockIdx.x * 256 + threadIdx.x;   // 0..32767
    const int tl = id & 15;
    const int bt = id >> 4;                          // b*64 + tt
    const int t  = (bt & 63) * 16 + tl;
    const int b  = bt >> 6;
    const float lt = lam[b * TT + t];
    float A = 0.f, W = 0.f, Y = 0.f;
    #pragma unroll
    for (int c = 15; c >= 0; --c) {
        const int pi = (bt * 16 + c) * 16 + tl;
        float sc = __expf(-lt * A);
        W += Wp[pi] * sc;
        Y += Yp[pi] * sc;
        A += Tp[pi];
    }
    float r = Y / (W + 1e-6f);
    out[b * TT + t] = fminf(fmaxf(r, 0.01f), 0.99f);
}

extern "C" void kernel_launch(void* const* d_in, const int* in_sizes, int n_in,
                              void* d_out, int out_size, void* d_ws, size_t ws_size,
                              hipStream_t stream) {
    const float* y     = (const float*)d_in[0];
    const int*   seq   = (const int*)  d_in[1];
    const float* embd  = (const float*)d_in[2];
    const float* lam_w = (const float*)d_in[3];
    const float* lam_b = (const float*)d_in[4];
    float* out = (float*)d_out;

    unsigned short* xbf = (unsigned short*)d_ws;            // B*T*H bf16 = 8 MB
    float* lam = (float*)(xbf + (size_t)BB * TT * HH);      // 128 KB
    float* Wp  = lam + BB * TT;                             // 2 MB
    float* Yp  = Wp + 32768 * 16;                           // 2 MB
    float* Tp  = Yp + 32768 * 16;                           // 2 MB

    gather_norm<<<BB * TT / 8, 256, 0, stream>>>(seq, embd, lam_w, lam_b, xbf, lam);
    sim_part<<<32768 / 4, 256, 0, stream>>>(xbf, lam, y, Wp, Yp, Tp);
    merge_kernel<<<BB * TT / 256, 256, 0, stream>>>(Wp, Yp, Tp, lam, out);
}

// Round 6
// 152.357 us; speedup vs baseline: 1.0369x; 1.0369x over previous
//
#include <hip/hip_runtime.h>
#include <math.h>

#define BB 32
#define TT 1024
#define HH 128

typedef __attribute__((ext_vector_type(8))) short short8;
typedef __attribute__((ext_vector_type(4))) float floatx4;

__device__ __forceinline__ unsigned short f2bf(float f) {
    unsigned u = __float_as_uint(f);
    u += 0x7fffu + ((u >> 16) & 1u);
    return (unsigned short)(u >> 16);
}

// Kernel A: gather embedding rows, normalize (store bf16), compute lambda.
__global__ __launch_bounds__(256)
void gather_norm(const int* __restrict__ seq,
                 const float* __restrict__ embd,
                 const float* __restrict__ lam_w,
                 const float* __restrict__ lam_b,
                 unsigned short* __restrict__ xbf,
                 float* __restrict__ lam) {
    const int lane = threadIdx.x & 63;
    const int half = lane >> 5;
    const int l32  = lane & 31;
    const int row  = blockIdx.x * 8 + (threadIdx.x >> 6) * 2 + half;
    const int idx  = seq[row];
    float4 v = ((const float4*)(embd + (size_t)idx * HH))[l32];
    float4 w = ((const float4*)lam_w)[l32];
    float ss = v.x * v.x + v.y * v.y + v.z * v.z + v.w * v.w;
    float dw = v.x * w.x + v.y * w.y + v.z * w.z + v.w * w.w;
    #pragma unroll
    for (int off = 16; off > 0; off >>= 1) {
        ss += __shfl_xor(ss, off);
        dw += __shfl_xor(dw, off);
    }
    float inv = 1.0f / sqrtf(ss);
    unsigned b0 = f2bf(v.x * inv), b1 = f2bf(v.y * inv);
    unsigned b2 = f2bf(v.z * inv), b3 = f2bf(v.w * inv);
    uint2 o; o.x = b0 | (b1 << 16); o.y = b2 | (b3 << 16);
    ((uint2*)(xbf + (size_t)row * HH))[l32] = o;
    if (l32 == 0) lam[row] = expf(dw + lam_b[0]);
}

// Kernel B1: one wave per (b, t-tile, chunk of 8 s-tiles). The hot loop has
// ZERO cross-lane ops: each (quad,tile) accumulates local partials
//   S = sum(v), W = sum(v*exp(-lam*sufin)), Y = sum(v*exp(-lam*sufin)*y)
// using only in-lane suffixes. Cross-quad/cross-tile decay factors
// exp(-lam * D) are applied in ONE batched shuffle phase at the end
// (exp(-lam(sufin+D)) == exp(-lam*sufin)*exp(-lam*D)). Chunks are merged in
// kernel B2 with the same associative rescale.
__global__ __launch_bounds__(256)
void sim_part(const unsigned short* __restrict__ xbf,
              const float* __restrict__ lam,
              const float* __restrict__ y,
              float* __restrict__ Wp,
              float* __restrict__ Yp,
              float* __restrict__ Tp) {
    const int wid  = blockIdx.x * 4 + (threadIdx.x >> 6);  // 0..16383
    const int c    = wid & 7;             // chunk (s-tiles 8c..8c+7)
    const int tt   = (wid >> 3) & 63;     // t-tile
    const int b    = wid >> 9;
    const int lane = threadIdx.x & 63;
    const int tl   = lane & 15;
    const int quad = lane >> 4;
    const int pi   = wid * 16 + tl;

    if (c * 8 > tt) {                     // chunk entirely above diagonal
        if (quad == 0) { Wp[pi] = 0.f; Yp[pi] = 0.f; Tp[pi] = 0.f; }
        return;
    }

    const int t = tt * 16 + tl;
    const size_t rowbase = (size_t)b * TT;
    const float lam_t = lam[rowbase + t];
    const float* yb = y + rowbase;

    // preload Xq fragments (B operand), 4 K-steps of 32
    short8 bq[4];
    const short8* qrow = (const short8*)(xbf + (rowbase + t) * HH);
    #pragma unroll
    for (int kk = 0; kk < 4; kk++) bq[kk] = qrow[kk * 4 + quad];

    float S[8], W[8], Y[8];

    // ---- hot loop: fully independent tiles, no cross-lane ops ----
    #pragma unroll
    for (int j = 0; j < 8; j++) {
        const int s_base = (c * 8 + j) << 4;
        const short8* arow =
            (const short8*)(xbf + (rowbase + s_base + tl) * HH);
        floatx4 acc = {0.f, 0.f, 0.f, 0.f};
        #pragma unroll
        for (int kk = 0; kk < 4; kk++) {
            short8 af = arow[kk * 4 + quad];
            acc = __builtin_amdgcn_mfma_f32_16x16x32_bf16(af, bq[kk], acc, 0, 0, 0);
        }
        const int s0g = s_base + quad * 4;
        float v0 = (s0g + 0 < t) ? (acc[0] + 1.f) * 0.5f : 0.f;
        float v1 = (s0g + 1 < t) ? (acc[1] + 1.f) * 0.5f : 0.f;
        float v2 = (s0g + 2 < t) ? (acc[2] + 1.f) * 0.5f : 0.f;
        float v3 = (s0g + 3 < t) ? (acc[3] + 1.f) * 0.5f : 0.f;
        float suf3 = v3;
        float suf2 = v2 + suf3;
        float suf1 = v1 + suf2;
        float suf0 = v0 + suf1;
        float e0 = __expf(-lam_t * suf0);
        float e1 = __expf(-lam_t * suf1);
        float e2 = __expf(-lam_t * suf2);
        float e3 = __expf(-lam_t * suf3);
        float4 yv = ((const float4*)(yb + s_base))[quad];
        float w0 = v0 * e0, w1 = v1 * e1, w2 = v2 * e2, w3 = v3 * e3;
        S[j] = suf0;
        W[j] = (w0 + w1) + (w2 + w3);
        Y[j] = (w0 * yv.x + w1 * yv.y) + (w2 * yv.z + w3 * yv.w);
    }

    // ---- batched cross-quad exchange (32 independent bpermutes) ----
    float tT[8], hq[8];
    #pragma unroll
    for (int j = 0; j < 8; j++) {
        float q0 = __shfl(S[j], tl);
        float q1 = __shfl(S[j], tl + 16);
        float q2 = __shfl(S[j], tl + 32);
        float q3 = __shfl(S[j], tl + 48);
        tT[j] = (q0 + q1) + (q2 + q3);
        hq[j] = (quad < 1 ? q1 : 0.f) + (quad < 2 ? q2 : 0.f) +
                (quad < 3 ? q3 : 0.f);
    }

    // ---- suffix over tiles + apply deferred decay factors ----
    float above = 0.f, wl = 0.f, yl = 0.f;
    #pragma unroll
    for (int j = 7; j >= 0; --j) {
        float sc = __expf(-lam_t * (above + hq[j]));
        wl += W[j] * sc;
        yl += Y[j] * sc;
        above += tT[j];
    }

    // ---- cross-quad final reduce, store partials ----
    float Wt = __shfl(wl, tl) + __shfl(wl, tl + 16) +
               __shfl(wl, tl + 32) + __shfl(wl, tl + 48);
    float Yt = __shfl(yl, tl) + __shfl(yl, tl + 16) +
               __shfl(yl, tl + 32) + __shfl(yl, tl + 48);
    if (quad == 0) {
        Wp[pi] = Wt;
        Yp[pi] = Yt;
        Tp[pi] = above;   // chunk sim total (uniform across quads)
    }
}

// Kernel B2: merge the 8 chunk partials per (b, t). One thread per t.
__global__ __launch_bounds__(256)
void merge_kernel(const float* __restrict__ Wp,
                  const float* __restrict__ Yp,
                  const float* __restrict__ Tp,
                  const float* __restrict__ lam,
                  float* __restrict__ out) {
    const int id = blockIdx.x * 256 + threadIdx.x;   // 0..32767
    const int tl = id & 15;
    const int bt = id >> 4;                          // b*64 + tt
    const int t  = (bt & 63) * 16 + tl;
    const int b  = bt >> 6;
    const float lt = lam[b * TT + t];
    float A = 0.f, W = 0.f, Y = 0.f;
    #pragma unroll
    for (int c = 7; c >= 0; --c) {
        const int pi = (bt * 8 + c) * 16 + tl;
        float sc = __expf(-lt * A);
        W += Wp[pi] * sc;
        Y += Yp[pi] * sc;
        A += Tp[pi];
    }
    float r = Y / (W + 1e-6f);
    out[b * TT + t] = fminf(fmaxf(r, 0.01f), 0.99f);
}

extern "C" void kernel_launch(void* const* d_in, const int* in_sizes, int n_in,
                              void* d_out, int out_size, void* d_ws, size_t ws_size,
                              hipStream_t stream) {
    const float* y     = (const float*)d_in[0];
    const int*   seq   = (const int*)  d_in[1];
    const float* embd  = (const float*)d_in[2];
    const float* lam_w = (const float*)d_in[3];
    const float* lam_b = (const float*)d_in[4];
    float* out = (float*)d_out;

    unsigned short* xbf = (unsigned short*)d_ws;            // 8 MB
    float* lam = (float*)(xbf + (size_t)BB * TT * HH);      // 128 KB
    float* Wp  = lam + BB * TT;                             // 1 MB
    float* Yp  = Wp + 16384 * 16;                           // 1 MB
    float* Tp  = Yp + 16384 * 16;                           // 1 MB

    gather_norm<<<BB * TT / 8, 256, 0, stream>>>(seq, embd, lam_w, lam_b, xbf, lam);
    sim_part<<<16384 / 4, 256, 0, stream>>>(xbf, lam, y, Wp, Yp, Tp);
    merge_kernel<<<BB * TT / 256, 256, 0, stream>>>(Wp, Yp, Tp, lam, out);
}

// Round 7
// 104.565 us; speedup vs baseline: 1.5108x; 1.4571x over previous
//
#include <hip/hip_runtime.h>
#include <math.h>

#define BB 32
#define TT 1024
#define HH 128

typedef __attribute__((ext_vector_type(8))) short short8;
typedef __attribute__((ext_vector_type(4))) float floatx4;

__device__ __forceinline__ unsigned short f2bf(float f) {
    unsigned u = __float_as_uint(f);
    u += 0x7fffu + ((u >> 16) & 1u);
    return (unsigned short)(u >> 16);
}

// Kernel A: gather embedding rows, normalize (store bf16), compute lambda.
__global__ __launch_bounds__(256)
void gather_norm(const int* __restrict__ seq,
                 const float* __restrict__ embd,
                 const float* __restrict__ lam_w,
                 const float* __restrict__ lam_b,
                 unsigned short* __restrict__ xbf,
                 float* __restrict__ lam) {
    const int lane = threadIdx.x & 63;
    const int half = lane >> 5;
    const int l32  = lane & 31;
    const int row  = blockIdx.x * 8 + (threadIdx.x >> 6) * 2 + half;
    const int idx  = seq[row];
    float4 v = ((const float4*)(embd + (size_t)idx * HH))[l32];
    float4 w = ((const float4*)lam_w)[l32];
    float ss = v.x * v.x + v.y * v.y + v.z * v.z + v.w * v.w;
    float dw = v.x * w.x + v.y * w.y + v.z * w.z + v.w * w.w;
    #pragma unroll
    for (int off = 16; off > 0; off >>= 1) {
        ss += __shfl_xor(ss, off);
        dw += __shfl_xor(dw, off);
    }
    float inv = 1.0f / sqrtf(ss);
    unsigned b0 = f2bf(v.x * inv), b1 = f2bf(v.y * inv);
    unsigned b2 = f2bf(v.z * inv), b3 = f2bf(v.w * inv);
    uint2 o; o.x = b0 | (b1 << 16); o.y = b2 | (b3 << 16);
    ((uint2*)(xbf + (size_t)row * HH))[l32] = o;
    if (l32 == 0) lam[row] = expf(dw + lam_b[0]);
}

// Per-(tile,group) local partials: sims from acc, in-lane suffix, local decay.
// No cross-lane ops. S = in-quad sim total, W/Y = locally-decayed sums.
__device__ __forceinline__ void tile_part(const floatx4& acc, int s0, int t,
                                          float lmt, const float4& yv,
                                          float& S, float& W, float& Y) {
    float v0 = (s0 + 0 < t) ? (acc[0] + 1.f) * 0.5f : 0.f;
    float v1 = (s0 + 1 < t) ? (acc[1] + 1.f) * 0.5f : 0.f;
    float v2 = (s0 + 2 < t) ? (acc[2] + 1.f) * 0.5f : 0.f;
    float v3 = (s0 + 3 < t) ? (acc[3] + 1.f) * 0.5f : 0.f;
    float suf3 = v3;
    float suf2 = v2 + suf3;
    float suf1 = v1 + suf2;
    float suf0 = v0 + suf1;
    float e0 = __expf(-lmt * suf0);
    float e1 = __expf(-lmt * suf1);
    float e2 = __expf(-lmt * suf2);
    float e3 = __expf(-lmt * suf3);
    float w0 = v0 * e0, w1 = v1 * e1, w2 = v2 * e2, w3 = v3 * e3;
    S = suf0;
    W = (w0 + w1) + (w2 + w3);
    Y = (w0 * yv.x + w1 * yv.y) + (w2 * yv.z + w3 * yv.w);
}

// Cross-quad resolution for one (tile,group): deferred decay factors applied,
// running 'above' updated. (exp(-lam(sufin+D)) == exp(-lam sufin)*exp(-lam D))
__device__ __forceinline__ void resolve(float S, float W, float Y, float lmt,
                                        int tl, int quad,
                                        float& above, float& wl, float& yl) {
    float q0 = __shfl(S, tl);
    float q1 = __shfl(S, tl + 16);
    float q2 = __shfl(S, tl + 32);
    float q3 = __shfl(S, tl + 48);
    float tT = (q0 + q1) + (q2 + q3);
    float hq = (quad < 1 ? q1 : 0.f) + (quad < 2 ? q2 : 0.f) +
               (quad < 3 ? q3 : 0.f);
    float sc = __expf(-lmt * (above + hq));
    wl += W * sc;
    yl += Y * sc;
    above += tT;
}

// Kernel B: one block per (b, u = 32-t supertile). 4 waves split the s-range
// (wave 3 = highest s); each wave computes BOTH 16-t groups of the supertile
// (t-pairing: one A-tile load feeds 8 MFMAs). Sub-batches of 2 s-tiles with
// all loads hoisted before the MFMAs (MLP). In-block LDS merge via the
// associative rescale exp(-lam * T_above).
__global__ __launch_bounds__(256, 4)
void sim_fused(const unsigned short* __restrict__ xbf,
               const float* __restrict__ lam,
               const float* __restrict__ y,
               float* __restrict__ out) {
    const int b    = blockIdx.x & 31;
    const int u    = 31 - (blockIdx.x >> 5);     // largest supertiles first
    const int tid  = threadIdx.x;
    const int w    = tid >> 6;
    const int lane = tid & 63;
    const int tl   = lane & 15;
    const int quad = lane >> 4;

    const size_t rowbase = (size_t)b * TT;
    const int t0 = u * 32 + tl;
    const int t1 = t0 + 16;
    const float lam0 = lam[rowbase + t0];
    const float lam1 = lam[rowbase + t1];
    const float* yb = y + rowbase;

    __shared__ float Wc[4][2][16], Yc[4][2][16], Tc[4][2][16];

    // preload both B-fragment sets (t-tile 2u and 2u+1)
    short8 bq0[4], bq1[4];
    const short8* q0r = (const short8*)(xbf + (rowbase + t0) * HH);
    const short8* q1r = (const short8*)(xbf + (rowbase + t1) * HH);
    #pragma unroll
    for (int kk = 0; kk < 4; kk++) {
        bq0[kk] = q0r[kk * 4 + quad];
        bq1[kk] = q1r[kk * 4 + quad];
    }

    // wave's contiguous range of 16-wide s-tiles
    const int nst = 2 * u + 2;
    const int qn = nst >> 2, rem = nst & 3;
    const int cnt   = qn + (w < rem ? 1 : 0);
    const int start = w * qn + (w < rem ? w : rem);

    float wl0 = 0.f, yl0 = 0.f, above0 = 0.f;
    float wl1 = 0.f, yl1 = 0.f, above1 = 0.f;

    const int nsb = (cnt + 1) >> 1;
    for (int sb = nsb - 1; sb >= 0; --sb) {
        const int jA = start + 2 * sb;          // lower s-tile
        const int jB = jA + 1;                  // higher s-tile (maybe invalid)
        const bool vB = (2 * sb + 1) < cnt;
        const int sbaseA = jA << 4;
        const int sbaseB = vB ? (jB << 4) : 0;

        // ---- hoist ALL loads for the sub-batch (8 A-frags + 2 y-vecs) ----
        const short8* arA = (const short8*)(xbf + (rowbase + sbaseA + tl) * HH);
        const short8* arB = (const short8*)(xbf + (rowbase + sbaseB + tl) * HH);
        short8 afA[4], afB[4];
        #pragma unroll
        for (int kk = 0; kk < 4; kk++) {
            afA[kk] = arA[kk * 4 + quad];
            afB[kk] = arB[kk * 4 + quad];
        }
        float4 yvA = ((const float4*)(yb + sbaseA))[quad];
        float4 yvB = ((const float4*)(yb + sbaseB))[quad];

        // ---- 16 MFMAs, 4 independent acc chains ----
        floatx4 aA0 = {0,0,0,0}, aA1 = {0,0,0,0};
        floatx4 aB0 = {0,0,0,0}, aB1 = {0,0,0,0};
        #pragma unroll
        for (int kk = 0; kk < 4; kk++) {
            aA0 = __builtin_amdgcn_mfma_f32_16x16x32_bf16(afA[kk], bq0[kk], aA0, 0, 0, 0);
            aA1 = __builtin_amdgcn_mfma_f32_16x16x32_bf16(afA[kk], bq1[kk], aA1, 0, 0, 0);
            aB0 = __builtin_amdgcn_mfma_f32_16x16x32_bf16(afB[kk], bq0[kk], aB0, 0, 0, 0);
            aB1 = __builtin_amdgcn_mfma_f32_16x16x32_bf16(afB[kk], bq1[kk], aB1, 0, 0, 0);
        }

        const int s0A = sbaseA + quad * 4;
        const int s0B = vB ? (sbaseB + quad * 4) : 0x40000000;  // masks all

        // ---- local partials (no cross-lane) ----
        float SB0, WB0, YB0, SB1, WB1, YB1;
        float SA0, WA0, YA0, SA1, WA1, YA1;
        tile_part(aB0, s0B, t0, lam0, yvB, SB0, WB0, YB0);
        tile_part(aB1, s0B, t1, lam1, yvB, SB1, WB1, YB1);
        tile_part(aA0, s0A, t0, lam0, yvA, SA0, WA0, YA0);
        tile_part(aA1, s0A, t1, lam1, yvA, SA1, WA1, YA1);

        // ---- resolution: tile B (higher s) first, then tile A ----
        resolve(SB0, WB0, YB0, lam0, tl, quad, above0, wl0, yl0);
        resolve(SB1, WB1, YB1, lam1, tl, quad, above1, wl1, yl1);
        resolve(SA0, WA0, YA0, lam0, tl, quad, above0, wl0, yl0);
        resolve(SA1, WA1, YA1, lam1, tl, quad, above1, wl1, yl1);
    }

    // ---- cross-quad final reduce, wave partials to LDS ----
    float Wt0 = __shfl(wl0, tl) + __shfl(wl0, tl + 16) +
                __shfl(wl0, tl + 32) + __shfl(wl0, tl + 48);
    float Yt0 = __shfl(yl0, tl) + __shfl(yl0, tl + 16) +
                __shfl(yl0, tl + 32) + __shfl(yl0, tl + 48);
    float Wt1 = __shfl(wl1, tl) + __shfl(wl1, tl + 16) +
                __shfl(wl1, tl + 32) + __shfl(wl1, tl + 48);
    float Yt1 = __shfl(yl1, tl) + __shfl(yl1, tl + 16) +
                __shfl(yl1, tl + 32) + __shfl(yl1, tl + 48);
    if (quad == 0) {
        Wc[w][0][tl] = Wt0; Yc[w][0][tl] = Yt0; Tc[w][0][tl] = above0;
        Wc[w][1][tl] = Wt1; Yc[w][1][tl] = Yt1; Tc[w][1][tl] = above1;
    }
    __syncthreads();

    // ---- merge 4 wave-chunks (wave 3 = highest s, no rescale) ----
    if (tid < 32) {
        const int g = tid >> 4, l = tid & 15;
        const int t = u * 32 + g * 16 + l;
        const float lt = lam[rowbase + t];
        float A = 0.f, W = 0.f, Y = 0.f;
        #pragma unroll
        for (int ww = 3; ww >= 0; --ww) {
            float sc = __expf(-lt * A);
            W += Wc[ww][g][l] * sc;
            Y += Yc[ww][g][l] * sc;
            A += Tc[ww][g][l];
        }
        float r = Y / (W + 1e-6f);
        out[rowbase + t] = fminf(fmaxf(r, 0.01f), 0.99f);
    }
}

extern "C" void kernel_launch(void* const* d_in, const int* in_sizes, int n_in,
                              void* d_out, int out_size, void* d_ws, size_t ws_size,
                              hipStream_t stream) {
    const float* y     = (const float*)d_in[0];
    const int*   seq   = (const int*)  d_in[1];
    const float* embd  = (const float*)d_in[2];
    const float* lam_w = (const float*)d_in[3];
    const float* lam_b = (const float*)d_in[4];
    float* out = (float*)d_out;

    unsigned short* xbf = (unsigned short*)d_ws;            // 8 MB
    float* lam = (float*)(xbf + (size_t)BB * TT * HH);      // 128 KB

    gather_norm<<<BB * TT / 8, 256, 0, stream>>>(seq, embd, lam_w, lam_b, xbf, lam);
    sim_fused<<<BB * 32, 256, 0, stream>>>(xbf, lam, y, out);
}